// Round 4
// baseline (358.353 us; speedup 1.0000x reference)
//
#include <hip/hip_runtime.h>
#include <math.h>

// img (16,8,512,512) fp32, params (16,3) fp32, out (16,8,512,512) fp32.
// Round 4: NO LDS. Rounds 0-3 proved the kernel is pinned at ~90us by the
// global_load_lds read path (~7.3 B/cyc/CU in every configuration, invariant
// to request width 4B/16B and wave count 12/32 -> shallow DMA return queue x
// loaded latency). The per-(tile,channel) tap footprint is ~12 KB < L1 32 KiB
// with ~4x bilinear reuse, so we gather the 4 taps per pixel DIRECTLY from
// global memory: L1 serves the reuse, reads ride the deep vmcnt-tracked vmem
// path, and there are no barriers / vmcnt convoys / LDS at all. Weights and
// tap offsets are computed once per pixel and reused for all 8 channels via
// uniform-base + 32-bit-offset (saddr) loads.
// Per-pixel fp math is bit-identical to the verified round-0..3 kernels:
// tap value = img[clamped coord], weight pre-multiplied by validity (0 for
// OOB) — exactly the reference's clipped gather.
constexpr int B = 16, C = 8, H = 512, W = 512;
constexpr int HW = H * W;
constexpr int TILE = 32;           // 32x32 output tile per block

__global__ __launch_bounds__(256, 6) void grid_sampler_kernel(
    const float* __restrict__ img,
    const float* __restrict__ params,
    float* __restrict__ out) {
    const int tid = threadIdx.x;

    // Bijective XCD swizzle: 4096 blocks = 8 XCDs x 512. Each XCD owns 2
    // whole batches (l>>8 = b), so an XCD's L2 only ever holds its own 2
    // image planes-sets; within an XCD consecutive blocks are x-adjacent
    // tiles (overlapping tap footprints) -> L2 hits.
    const int blk = (int)blockIdx.x;
    const int l   = (blk & 7) * 512 + (blk >> 3);
    const int b   = l >> 8;
    const int tt  = l & 255;
    const int ty0 = (tt >> 4) * TILE;
    const int tx0 = (tt & 15) * TILE;

    // Wave-uniform per-batch params.
    const float tpx = params[b * 3 + 0] * (1.0f / W);
    const float tpy = params[b * 3 + 1] * (1.0f / H);
    const float th  = params[b * 3 + 2];
    const float c = cosf(th), s = sinf(th);

    auto srcxy = [&](float x, float y, float& ix, float& iy) {
        float xs = (2.0f * x + 1.0f) * (1.0f / W) - 1.0f;
        float ys = (2.0f * y + 1.0f) * (1.0f / H) - 1.0f;
        float gx = c * xs - s * ys + tpx;
        float gy = s * xs + c * ys + tpy;
        ix = ((gx + 1.0f) * (float)W - 1.0f) * 0.5f;
        iy = ((gy + 1.0f) * (float)H - 1.0f) * 0.5f;
    };

    // Thread -> one output row, 4 consecutive cols (float4 store).
    const int oy  = ty0 + (tid >> 3);
    const int oxb = tx0 + (tid & 7) * 4;

    // Per-pixel setup ONCE, reused by all 8 channels. Tap offsets are
    // clamped in-image 32-bit element offsets; invalid taps carry weight 0
    // (identical arithmetic to the reference's clipped gather).
    int   o00[4], o01[4], o10[4], o11[4];
    float w00[4], w01[4], w10[4], w11[4];
#pragma unroll
    for (int j = 0; j < 4; ++j) {
        float ix, iy;
        srcxy((float)(oxb + j), (float)oy, ix, iy);
        const float x0f = floorf(ix), y0f = floorf(iy);
        const int x0 = (int)x0f, y0 = (int)y0f;
        const int x1 = x0 + 1,  y1 = y0 + 1;
        const float wx1 = ix - x0f, wx0 = 1.0f - wx1;
        const float wy1 = iy - y0f, wy0 = 1.0f - wy1;
        const float vx0 = (x0 >= 0 && x0 < W) ? 1.0f : 0.0f;
        const float vx1 = (x1 >= 0 && x1 < W) ? 1.0f : 0.0f;
        const float vy0 = (y0 >= 0 && y0 < H) ? 1.0f : 0.0f;
        const float vy1 = (y1 >= 0 && y1 < H) ? 1.0f : 0.0f;
        w00[j] = wy0 * wx0 * vy0 * vx0;
        w01[j] = wy0 * wx1 * vy0 * vx1;
        w10[j] = wy1 * wx0 * vy1 * vx0;
        w11[j] = wy1 * wx1 * vy1 * vx1;
        const int x0c = min(max(x0, 0), W - 1);
        const int x1c = min(max(x1, 0), W - 1);
        const int y0c = min(max(y0, 0), H - 1);
        const int y1c = min(max(y1, 0), H - 1);
        const int r0 = y0c * W, r1 = y1c * W;
        o00[j] = r0 + x0c;  o01[j] = r0 + x1c;
        o10[j] = r1 + x0c;  o11[j] = r1 + x1c;
    }

    // Channel loop: uniform plane base (saddr form), divergent 32-bit
    // offsets; 16 independent tap loads in flight per iteration.
    const float* ip = img + (size_t)b * C * HW;   // wave-uniform
    float*       op = out + (size_t)b * C * HW;   // wave-uniform
    const int ooff = oy * W + oxb;
    for (int k = 0; k < C; ++k) {
        float4 v;
#pragma unroll
        for (int j = 0; j < 4; ++j) {
            const float t00 = ip[o00[j]], t01 = ip[o01[j]];
            const float t10 = ip[o10[j]], t11 = ip[o11[j]];
            ((float*)&v)[j] = t00 * w00[j] + t01 * w01[j]
                            + t10 * w10[j] + t11 * w11[j];
        }
        *(float4*)(op + ooff) = v;
        ip += HW; op += HW;
    }
}

extern "C" void kernel_launch(void* const* d_in, const int* in_sizes, int n_in,
                              void* d_out, int out_size, void* d_ws, size_t ws_size,
                              hipStream_t stream) {
    const float* img    = (const float*)d_in[0];
    const float* params = (const float*)d_in[1];
    float*       out    = (float*)d_out;

    constexpr int grid = B * (H / TILE) * (W / TILE);   // 4096 blocks
    grid_sampler_kernel<<<grid, 256, 0, stream>>>(img, params, out);
}

// Round 5
// 248.495 us; speedup vs baseline: 1.4421x; 1.4421x over previous
//
#include <hip/hip_runtime.h>
#include <math.h>

// img (16,8,512,512) fp32, params (16,3) fp32, out (16,8,512,512) fp32.
// Round 5: REG-STAGING. Rounds 0-3 pinned at ~4.5 TB/s of staged reads
// through the global_load_lds DMA engine, invariant to width/count/occupancy;
// round 4 proved per-lane gather is TA-bound (2.3x worse). This round keeps
// round 3's exact structure (window, LDS layout, gather math bit-identical)
// but stages through the PROVEN-fast path: global_load_dwordx4 -> VGPR ->
// ds_write_b128. Each wave: issue all 12 loads (4ch x 3, 48 VGPRs held);
// per channel: ds_write x3 (compiler inserts exact counted vmcnt for the
// dependency), lgkmcnt(0)+barrier, gather+store. Later channels' loads stay
// in flight under earlier channels' gathers.
constexpr int B = 16, C = 8, H = 512, W = 512;
constexpr int HW = H * W;
constexpr int TILE = 32;           // 32x32 output tile per block
constexpr int ROWS = 48;           // staged source rows (bbox span <= 46)
constexpr int CPB  = 4;            // channels per block
// Per-channel LDS chunk: [4 front pads][48*64 data][4 tail pads] floats.
// bp = chunk+4 (16B aligned). Reachable relative indices: [-1, 3072];
// bp[-1] (=chunk[3]) and bp[3072] (=chunk[3076]) are zeroed pad cells.
constexpr int CSTR = 4 + ROWS * 64 + 4;   // 3080 floats, 16B-aligned stride

#define BARRIER() asm volatile("s_waitcnt lgkmcnt(0)\n\ts_barrier" ::: "memory")

__global__ __launch_bounds__(256, 3) void grid_sampler_kernel(
    const float* __restrict__ img,
    const float* __restrict__ params,
    float* __restrict__ out) {
    __shared__ float lds[CPB * CSTR];
    const int tid = threadIdx.x;

    // Bijective XCD swizzle: 8192 blocks = 8 XCDs x 1024. Consecutive logical
    // ids = same (batch, channel-quad), adjacent tiles (overlapping staging
    // windows) -> same XCD L2.
    const int blk = (int)blockIdx.x;
    const int l   = (blk & 7) * 1024 + (blk >> 3);
    const int b   = l >> 9;              // (b, ch-quad, ty, tx) ordering
    const int cg  = (l >> 8) & 1;
    const int tt  = l & 255;
    const int ty0 = (tt >> 4) * TILE;
    const int tx0 = (tt & 15) * TILE;

    // Zero the 2 pad cells of each channel chunk (only unstaged cells any
    // (zero-weight) tap can reach; must be finite, LDS starts uninitialized).
    // Visible to all waves after the first BARRIER() below.
    if (tid < 2 * CPB) {
        const int k = tid >> 1;
        lds[k * CSTR + ((tid & 1) ? (4 + ROWS * 64) : 3)] = 0.0f;
    }

    // Wave-uniform per-batch params.
    const float tpx = params[b * 3 + 0] * (1.0f / W);
    const float tpy = params[b * 3 + 1] * (1.0f / H);
    const float th  = params[b * 3 + 2];
    const float c = cosf(th), s = sinf(th);

    // Identical fp expression for bbox corners and per-pixel sampling; gx/gy
    // monotone in x,y (per fixed other coord) so corner min bounds every pixel.
    auto srcxy = [&](float x, float y, float& ix, float& iy) {
        float xs = (2.0f * x + 1.0f) * (1.0f / W) - 1.0f;
        float ys = (2.0f * y + 1.0f) * (1.0f / H) - 1.0f;
        float gx = c * xs - s * ys + tpx;
        float gy = s * xs + c * ys + tpy;
        ix = ((gx + 1.0f) * (float)W - 1.0f) * 0.5f;
        iy = ((gy + 1.0f) * (float)H - 1.0f) * 0.5f;
    };

    float ixa, iya, ixb, iyb, ixc, iyc, ixd, iyd;
    srcxy((float)tx0,             (float)ty0,             ixa, iya);
    srcxy((float)(tx0 + TILE-1),  (float)ty0,             ixb, iyb);
    srcxy((float)tx0,             (float)(ty0 + TILE-1),  ixc, iyc);
    srcxy((float)(tx0 + TILE-1),  (float)(ty0 + TILE-1),  ixd, iyd);
    const float ixmin = fminf(fminf(ixa, ixb), fminf(ixc, ixd));
    const float iymin = fminf(fminf(iya, iyb), fminf(iyc, iyd));
    const int xlo = min(max((int)floorf(ixmin), 0), W - 1);
    const int ylo = min(max((int)floorf(iymin), 0), H - 1);
    // Exact staging window: 64 cols starting at xs0 (4-float aligned, fully
    // in-image). Bbox x-span <= 44; alignment wastes <= 3 cols and the
    // 1-texel left margin <= 1, so 64 always covers every valid tap.
    const int xs0 = max(0, min((xlo - 1) & ~3, W - 64));
    const int yls = min(ylo, H - ROWS);  // rows always in-image

    // Issue ALL channel loads up front (deep vmem queue, 48 VGPRs held).
    // Wave wv owns rows [12wv, 12wv+12) of every channel; lane i covers
    // row +(i>>4), colblock (i&15)*4 of each 4-row group.
    const size_t plane = (size_t)(b * C + CPB * cg) * HW;  // channel-quad base
    const int wv = tid >> 6, ln = tid & 63;
    const float* srcL = img + plane + (size_t)yls * W + xs0
                      + (size_t)(ln >> 4) * W + (ln & 15) * 4;
    float4 vl[CPB][3];
#pragma unroll
    for (int k = 0; k < CPB; ++k) {
#pragma unroll
        for (int j2 = 0; j2 < 3; ++j2) {
            const int rg = 12 * wv + 4 * j2;   // row-group base
            vl[k][j2] = *(const float4*)(srcL + (size_t)k * HW + (size_t)rg * W);
        }
    }
    // Pin: all loads issued before any staging wait below.
    asm volatile("" ::: "memory");

    // Per-pixel setup ONCE (overlaps the load flight), reused by 4 channels.
    const int oy  = ty0 + (tid >> 3);
    const int oxb = tx0 + (tid & 7) * 4;
    int   a0[4], a1[4];
    float w00[4], w01[4], w10[4], w11[4];
#pragma unroll
    for (int j = 0; j < 4; ++j) {
        float ix, iy;
        srcxy((float)(oxb + j), (float)oy, ix, iy);
        const float x0f = floorf(ix), y0f = floorf(iy);
        const int x0 = (int)x0f, y0 = (int)y0f;
        const int x1 = x0 + 1,  y1 = y0 + 1;
        const float wx1 = ix - x0f, wx0 = 1.0f - wx1;
        const float wy1 = iy - y0f, wy0 = 1.0f - wy1;
        const float vx0 = (x0 >= 0 && x0 < W) ? 1.0f : 0.0f;
        const float vx1 = (x1 >= 0 && x1 < W) ? 1.0f : 0.0f;
        const float vy0 = (y0 >= 0 && y0 < H) ? 1.0f : 0.0f;
        const float vy1 = (y1 >= 0 && y1 < H) ? 1.0f : 0.0f;
        w00[j] = wy0 * wx0 * vy0 * vx0;
        w01[j] = wy0 * wx1 * vy0 * vx1;
        w10[j] = wy1 * wx0 * vy1 * vx0;
        w11[j] = wy1 * wx1 * vy1 * vx1;
        // Valid x0 -> xi = x0-xs0 in [0,63] exact (window covers bbox).
        // x0=-1 (0-wt) -> xi=-1 hits the zeroed front pad; its x1 tap reads
        // bp[yi*64] = image col 0 (correct). xi=63's +1 tap hits the next
        // row's col 0 or the zeroed tail pad, always 0-weight & finite.
        const int xi  = min(max(x0 - xs0, -1), 63);
        const int yi0 = min(max(y0 - yls, 0), ROWS - 1);
        const int yi1 = min(max(y1 - yls, 0), ROWS - 1);
        a0[j] = yi0 * 64 + xi;
        a1[j] = yi1 * 64 + xi;
    }
    const int ooff = oy * W + oxb;

    // Per channel: ds_write its 12 rows (compiler emits the exact counted
    // vmcnt for vl[k]'s loads), barrier, gather, store. Chunks are disjoint
    // so one barrier per channel suffices; later channels' loads + earlier
    // stores remain in flight throughout.
#pragma unroll
    for (int k = 0; k < CPB; ++k) {
        float* chunk = &lds[k * CSTR + 4];
#pragma unroll
        for (int j2 = 0; j2 < 3; ++j2) {
            const int rg = 12 * wv + 4 * j2;
            // Rows rg..rg+3 are contiguous (64-float rows): wave writes one
            // contiguous 1 KB block -> conflict-free ds_write_b128.
            *(float4*)(chunk + rg * 64 + (ln >> 4) * 64 + (ln & 15) * 4) =
                vl[k][j2];
        }
        BARRIER();
        const float* bp = chunk;
        float4 v;
#pragma unroll
        for (int j = 0; j < 4; ++j) {
            const float t00 = bp[a0[j]], t01 = bp[a0[j] + 1];
            const float t10 = bp[a1[j]], t11 = bp[a1[j] + 1];
            ((float*)&v)[j] = t00 * w00[j] + t01 * w01[j]
                            + t10 * w10[j] + t11 * w11[j];
        }
        *(float4*)(out + plane + (size_t)k * HW + ooff) = v;
    }
}

extern "C" void kernel_launch(void* const* d_in, const int* in_sizes, int n_in,
                              void* d_out, int out_size, void* d_ws, size_t ws_size,
                              hipStream_t stream) {
    const float* img    = (const float*)d_in[0];
    const float* params = (const float*)d_in[1];
    float*       out    = (float*)d_out;

    constexpr int grid = B * (C / CPB) * (H / TILE) * (W / TILE);  // 8192
    grid_sampler_kernel<<<grid, 256, 0, stream>>>(img, params, out);
}